// Round 2
// baseline (594.673 us; speedup 1.0000x reference)
//
#include <hip/hip_runtime.h>

#define EDGES 800000
#define NODES 50000
#define CH 28        // NS + 3*NV
#define NWT 400      // n_weights
#define CAP 96       // per-node edge-list capacity (Poisson(16) => P(deg>96) ~ 0)

typedef __attribute__((ext_vector_type(8))) short bf16x8;
typedef __attribute__((ext_vector_type(4))) float f32x4;

__device__ __forceinline__ short f2bf(float f) {
    union { float f; unsigned u; } v; v.f = f;
    unsigned r = v.u + 0x7FFFu + ((v.u >> 16) & 1u);   // RNE
    return (short)(r >> 16);
}

// XOR swizzle for 128B-row LDS tiles (breaks 16-way conflict on b128 column reads)
#define SWZ(b, row) ((b) ^ (((row) & 7) << 4))

// ============================================================================
// K1: per-edge MLP + tensor product -> out_e rows (linear) + CSR-lite lists
// ============================================================================
template <int SCATTER>   // SCATTER=0: write oute+list; SCATTER=1: legacy atomic path
__global__ __launch_bounds__(256, 2) void tpconv_kernel(
    const float* __restrict__ node_attr,
    const float* __restrict__ edge_attr,
    const float* __restrict__ edge_sh,
    const int*   __restrict__ eidx,
    const float* __restrict__ W1,
    const float* __restrict__ b1,
    const float* __restrict__ W2,
    const float* __restrict__ b2,
    float* __restrict__ oute,      // SCATTER=0: [E][28]   | SCATTER=1: outacc [N][28]
    int*   __restrict__ list,      // SCATTER=0: [N][CAP]  | SCATTER=1: unused
    int*   __restrict__ cnt)       // SCATTER=0: int histo | SCATTER=1: float cnt
{
    __shared__ __align__(16) short w2t[NWT * 64];   // W2^T bf16, swizzled
    __shared__ float b2s[NWT];
    __shared__ __align__(16) short hbuf[4][16 * 64]; // per-wave h tile, swizzled
    __shared__ float edata[4][16 * 53];              // per-wave per-edge coefficients
    __shared__ int   srcb[4][16];

    const int tid  = threadIdx.x;
    const int lane = tid & 63;
    const int wid  = tid >> 6;
    const int cl   = lane & 15;   // col within fragment
    const int qd   = lane >> 4;   // lane quad

    // ---- stage W2^T (bf16, swizzled) + b2 : once per block ----
    for (int f = tid; f < NWT * 64; f += 256) {
        int n = f >> 6, j = f & 63;
        int byte = SWZ(n * 128 + j * 2, n);
        w2t[byte >> 1] = f2bf(W2[j * NWT + n]);
    }
    for (int f = tid; f < NWT; f += 256) b2s[f] = b2[f];

    // ---- per-lane W1 fragments (B of GEMM1) + b1 ----
    float b1v[4];
    bf16x8 w1f[2][4];
    #pragma unroll
    for (int nt = 0; nt < 4; ++nt) {
        b1v[nt] = b1[nt * 16 + cl];
        #pragma unroll
        for (int ks = 0; ks < 2; ++ks) {
            bf16x8 fr;
            #pragma unroll
            for (int i = 0; i < 8; ++i) {
                int k = ks * 32 + qd * 8 + i;
                fr[i] = f2bf(W1[k * 64 + nt * 16 + cl]);
            }
            w1f[ks][nt] = fr;
        }
    }
    __syncthreads();

    const float INV3 = 0.57735026919f;      // 1/sqrt(3)
    const float CS_  = 0.17677669529f;      // (1/sqrt(16)) * (1/sqrt(2))
    const float CV_  = 0.35355339059f;      // (1/sqrt(4))  * (1/sqrt(2))

    const int tiles = EDGES / 16;           // 50000, exact
    for (int tile = blockIdx.x * 4 + wid; tile < tiles; tile += gridDim.x * 4) {
        const int ebase = tile * 16;

        // ---- per-edge coefficient precompute (lanes 0..15, one edge each) ----
        if (lane < 16) {
            const int e  = ebase + lane;
            const int s  = eidx[e];
            const int dn = eidx[EDGES + e];
            if (SCATTER) {
                srcb[wid][lane] = s;
                atomicAdd((float*)cnt, 0.0f); // keep signature; real cnt below
                atomicAdd(((float*)cnt) + s, 1.0f);
            } else {
                int slot = atomicAdd(&cnt[s], 1);
                if (slot < CAP) list[s * CAP + slot] = e;
            }
            const float4 sh4 = *reinterpret_cast<const float4*>(edge_sh + (size_t)e * 4);
            float xs[16], xv[12];
            {
                const float4* xp = reinterpret_cast<const float4*>(node_attr + (size_t)dn * CH);
                float4 q0 = xp[0], q1 = xp[1], q2 = xp[2], q3 = xp[3], q4 = xp[4], q5 = xp[5], q6 = xp[6];
                xs[0]=q0.x; xs[1]=q0.y; xs[2]=q0.z; xs[3]=q0.w;
                xs[4]=q1.x; xs[5]=q1.y; xs[6]=q1.z; xs[7]=q1.w;
                xs[8]=q2.x; xs[9]=q2.y; xs[10]=q2.z; xs[11]=q2.w;
                xs[12]=q3.x; xs[13]=q3.y; xs[14]=q3.z; xs[15]=q3.w;
                xv[0]=q4.x; xv[1]=q4.y; xv[2]=q4.z; xv[3]=q4.w;
                xv[4]=q5.x; xv[5]=q5.y; xv[6]=q5.z; xv[7]=q5.w;
                xv[8]=q6.x; xv[9]=q6.y; xv[10]=q6.z; xv[11]=q6.w;
            }
            const float shs = sh4.x, sv0 = sh4.y, sv1 = sh4.z, sv2 = sh4.w;
            float* ed = &edata[wid][lane * 53];
            #pragma unroll
            for (int i = 0; i < 16; ++i) {
                ed[i]      = xs[i] * shs * CS_;   // a_s  (w_ss coeff)
                ed[20 + i] = xs[i] * CS_;         // b_s  (w_sv coeff)
            }
            #pragma unroll
            for (int v = 0; v < 4; ++v) {
                float dot = (xv[3*v] * sv0 + xv[3*v+1] * sv1 + xv[3*v+2] * sv2) * INV3;
                ed[16 + v] = dot * CV_;           // a_v  (w_vs coeff)
                ed[36 + 3*v + 0] = xv[3*v + 0] * shs * CV_;   // xvs (w_vv coeff)
                ed[36 + 3*v + 1] = xv[3*v + 1] * shs * CV_;
                ed[36 + 3*v + 2] = xv[3*v + 2] * shs * CV_;
            }
            ed[48] = sv0; ed[49] = sv1; ed[50] = sv2;
        }

        // ---- GEMM1 A fragments straight from global (f32 -> bf16) ----
        const float4* ap = reinterpret_cast<const float4*>(edge_attr + (size_t)(ebase + cl) * 64);
        float4 a0 = ap[qd*2], a1 = ap[qd*2 + 1], a2 = ap[8 + qd*2], a3 = ap[8 + qd*2 + 1];
        bf16x8 af0, af1;
        af0[0]=f2bf(a0.x); af0[1]=f2bf(a0.y); af0[2]=f2bf(a0.z); af0[3]=f2bf(a0.w);
        af0[4]=f2bf(a1.x); af0[5]=f2bf(a1.y); af0[6]=f2bf(a1.z); af0[7]=f2bf(a1.w);
        af1[0]=f2bf(a2.x); af1[1]=f2bf(a2.y); af1[2]=f2bf(a2.z); af1[3]=f2bf(a2.w);
        af1[4]=f2bf(a3.x); af1[5]=f2bf(a3.y); af1[6]=f2bf(a3.z); af1[7]=f2bf(a3.w);

        // ---- GEMM1: h = relu(A @ W1 + b1), write bf16 h tile to LDS ----
        short* hb = hbuf[wid];
        #pragma unroll
        for (int nt = 0; nt < 4; ++nt) {
            f32x4 acc = { b1v[nt], b1v[nt], b1v[nt], b1v[nt] };
            acc = __builtin_amdgcn_mfma_f32_16x16x32_bf16(af0, w1f[0][nt], acc, 0, 0, 0);
            acc = __builtin_amdgcn_mfma_f32_16x16x32_bf16(af1, w1f[1][nt], acc, 0, 0, 0);
            #pragma unroll
            for (int r = 0; r < 4; ++r) {
                int m = qd * 4 + r;
                float hv = fmaxf(acc[r], 0.0f);
                int byte = SWZ(m * 128 + (nt * 16 + cl) * 2, m);
                hb[byte >> 1] = f2bf(hv);
            }
        }

        // ---- h fragments back (A of GEMM2); same-wave LDS, no barrier needed ----
        bf16x8 h0 = *reinterpret_cast<bf16x8*>(reinterpret_cast<char*>(hb) + SWZ(cl * 128 + qd * 16, cl));
        bf16x8 h1 = *reinterpret_cast<bf16x8*>(reinterpret_cast<char*>(hb) + SWZ(cl * 128 + 64 + qd * 16, cl));

        // ---- GEMM2 over 25 column tiles, fused tensor-product consume ----
        f32x4 outs = {0.f, 0.f, 0.f, 0.f};
        f32x4 pacc = {0.f, 0.f, 0.f, 0.f};
        float qacc[4][3] = {{0.f,0.f,0.f},{0.f,0.f,0.f},{0.f,0.f,0.f},{0.f,0.f,0.f}};
        const float* edw = edata[wid];
        const char* wb = reinterpret_cast<const char*>(w2t);
        #pragma unroll
        for (int ct = 0; ct < 25; ++ct) {
            int n = ct * 16 + cl;
            bf16x8 bf0 = *reinterpret_cast<const bf16x8*>(wb + SWZ(n * 128 + qd * 16, n));
            bf16x8 bf1 = *reinterpret_cast<const bf16x8*>(wb + SWZ(n * 128 + 64 + qd * 16, n));
            float bb = b2s[n];
            f32x4 t = { bb, bb, bb, bb };
            t = __builtin_amdgcn_mfma_f32_16x16x32_bf16(h0, bf0, t, 0, 0, 0);
            t = __builtin_amdgcn_mfma_f32_16x16x32_bf16(h1, bf1, t, 0, 0, 0);
            if (ct < 16) {                       // w_ss
                #pragma unroll
                for (int r = 0; r < 4; ++r)
                    outs[r] += edw[(qd*4 + r) * 53 + ct] * t[r];
            } else if (ct < 20) {                // w_vs
                #pragma unroll
                for (int r = 0; r < 4; ++r)
                    outs[r] += edw[(qd*4 + r) * 53 + 16 + (ct - 16)] * t[r];
            } else if (ct < 24) {                // w_sv: P partial
                int il = cl >> 2;
                #pragma unroll
                for (int r = 0; r < 4; ++r)
                    pacc[r] += edw[(qd*4 + r) * 53 + 20 + 4*(ct - 20) + il] * t[r];
            } else {                             // w_vv: Q partial
                int v = cl >> 2;
                #pragma unroll
                for (int r = 0; r < 4; ++r) {
                    #pragma unroll
                    for (int d = 0; d < 3; ++d)
                        qacc[r][d] += edw[(qd*4 + r) * 53 + 36 + 3*v + d] * t[r];
                }
            }
        }

        // ---- out_s ----
        #pragma unroll
        for (int r = 0; r < 4; ++r) {
            int m = qd * 4 + r;
            if (SCATTER) {
                int s = srcb[wid][m];
                atomicAdd(&oute[(size_t)s * CH + cl], outs[r]);
            } else {
                oute[(size_t)(ebase + m) * CH + cl] = outs[r];
            }
        }
        // ---- butterfly-reduce P,Q over the 4 il/v sub-columns ----
        #pragma unroll
        for (int r = 0; r < 4; ++r) {
            float p = pacc[r];
            p += __shfl_xor(p, 4);
            p += __shfl_xor(p, 8);
            pacc[r] = p;
            #pragma unroll
            for (int d = 0; d < 3; ++d) {
                float q = qacc[r][d];
                q += __shfl_xor(q, 4);
                q += __shfl_xor(q, 8);
                qacc[r][d] = q;
            }
        }
        // ---- out_v: lane c<12 owns (o=c&3, d=c>>2) ----
        if (cl < 12) {
            int o = cl & 3, d = cl >> 2;
            #pragma unroll
            for (int r = 0; r < 4; ++r) {
                int m = qd * 4 + r;
                float qv = (d == 0) ? qacc[r][0] : ((d == 1) ? qacc[r][1] : qacc[r][2]);
                float val = edw[m * 53 + 48 + d] * pacc[r] + qv;
                if (SCATTER) {
                    int s = srcb[wid][m];
                    atomicAdd(&oute[(size_t)s * CH + 16 + o * 3 + d], val);
                } else {
                    oute[(size_t)(ebase + m) * CH + 16 + o * 3 + d] = val;
                }
            }
        }
    }
}

// ============================================================================
// K2: per-node gather of out_e rows, mean, +residual
// ============================================================================
__global__ __launch_bounds__(256) void gather_kernel(
    const float* __restrict__ oute, const int* __restrict__ list,
    const int* __restrict__ cnt, const float* __restrict__ node_attr,
    float* __restrict__ out)
{
    int gid = blockIdx.x * 256 + threadIdx.x;
    int n = gid >> 5, c = gid & 31;
    if (n >= NODES || c >= CH) return;
    int deg = cnt[n];
    int m = min(deg, CAP);
    float acc = 0.0f;
    for (int j = 0; j < m; ++j) {
        int e = list[n * CAP + j];
        acc += oute[(size_t)e * CH + c];
    }
    out[n * CH + c] = acc / fmaxf((float)deg, 1.0f) + node_attr[n * CH + c];
}

__global__ void finalize_kernel(float* __restrict__ out, const float* __restrict__ cnt,
                                const float* __restrict__ node_attr) {
    int idx = blockIdx.x * 256 + threadIdx.x;
    if (idx < NODES * CH) {
        int n = idx / CH;
        out[idx] = out[idx] / fmaxf(cnt[n], 1.0f) + node_attr[idx];
    }
}

extern "C" void kernel_launch(void* const* d_in, const int* in_sizes, int n_in,
                              void* d_out, int out_size, void* d_ws, size_t ws_size,
                              hipStream_t stream) {
    const float* node_attr = (const float*)d_in[0];
    const float* edge_attr = (const float*)d_in[1];
    const float* edge_sh   = (const float*)d_in[2];
    const int*   eidx      = (const int*)d_in[3];
    const float* W1 = (const float*)d_in[4];
    const float* b1 = (const float*)d_in[5];
    const float* W2 = (const float*)d_in[6];
    const float* b2 = (const float*)d_in[7];
    float* out = (float*)d_out;

    const size_t OUTE_BYTES = (size_t)EDGES * CH * sizeof(float);   // 89.6 MB
    const size_t LIST_BYTES = (size_t)NODES * CAP * sizeof(int);    // 19.2 MB
    const size_t CNT_BYTES  = (size_t)NODES * sizeof(int);          // 0.2 MB

    if (ws_size >= OUTE_BYTES + LIST_BYTES + CNT_BYTES) {
        float* oute = (float*)d_ws;
        int*   list = (int*)((char*)d_ws + OUTE_BYTES);
        int*   cnt  = (int*)((char*)d_ws + OUTE_BYTES + LIST_BYTES);
        hipMemsetAsync(cnt, 0, CNT_BYTES, stream);
        tpconv_kernel<0><<<512, 256, 0, stream>>>(node_attr, edge_attr, edge_sh, eidx,
                                                  W1, b1, W2, b2, oute, list, cnt);
        gather_kernel<<<(NODES * 32 + 255) / 256, 256, 0, stream>>>(oute, list, cnt,
                                                                    node_attr, out);
    } else {
        // fallback: legacy atomic-scatter path
        float* cntf = (float*)d_ws;
        hipMemsetAsync(d_out, 0, (size_t)NODES * CH * sizeof(float), stream);
        hipMemsetAsync(d_ws, 0, (size_t)NODES * sizeof(float), stream);
        tpconv_kernel<1><<<512, 256, 0, stream>>>(node_attr, edge_attr, edge_sh, eidx,
                                                  W1, b1, W2, b2, out, nullptr, (int*)cntf);
        finalize_kernel<<<(NODES * CH + 255) / 256, 256, 0, stream>>>(out, cntf, node_attr);
    }
}

// Round 3
// 269.939 us; speedup vs baseline: 2.2030x; 2.2030x over previous
//
#include <hip/hip_runtime.h>

#define EDGES 800000
#define NODES 50000
#define CH 28        // NS + 3*NV
#define NWT 400      // n_weights
#define SCAN_NB 196  // ceil(NODES/256)

typedef __attribute__((ext_vector_type(8))) short bf16x8;
typedef __attribute__((ext_vector_type(4))) float f32x4;

__device__ __forceinline__ short f2bf(float f) {
    union { float f; unsigned u; } v; v.f = f;
    unsigned r = v.u + 0x7FFFu + ((v.u >> 16) & 1u);   // RNE
    return (short)(r >> 16);
}

// XOR swizzle for 128B-row LDS tiles (breaks 16-way conflict on b128 column reads)
#define SWZ(b, row) ((b) ^ (((row) & 7) << 4))

// ============================================================================
// Sort prep: histogram -> exclusive scan (2-level) -> stable bucket placement
// ============================================================================
__global__ __launch_bounds__(256) void hist_kernel(const int* __restrict__ eidx,
                                                   int* __restrict__ counts) {
    int e = blockIdx.x * 256 + threadIdx.x;
    if (e < EDGES) atomicAdd(&counts[eidx[e]], 1);
}

__global__ __launch_bounds__(256) void scan1_kernel(const int* __restrict__ counts,
                                                    int* __restrict__ offsets,
                                                    int* __restrict__ bsum) {
    __shared__ int tmp[256];
    int t = threadIdx.x;
    int i = blockIdx.x * 256 + t;
    int v = (i < NODES) ? counts[i] : 0;
    tmp[t] = v;
    __syncthreads();
    int x = v;
    for (int d = 1; d < 256; d <<= 1) {
        int y = (t >= d) ? tmp[t - d] : 0;
        __syncthreads();
        x += y; tmp[t] = x;
        __syncthreads();
    }
    if (i < NODES) offsets[i] = x - v;          // exclusive within block
    if (t == 255) bsum[blockIdx.x] = x;         // block total
}

__global__ __launch_bounds__(256) void scan2_kernel(int* __restrict__ bsum) {
    __shared__ int tmp[256];
    int t = threadIdx.x;
    int v = (t < SCAN_NB) ? bsum[t] : 0;
    tmp[t] = v;
    __syncthreads();
    int x = v;
    for (int d = 1; d < 256; d <<= 1) {
        int y = (t >= d) ? tmp[t - d] : 0;
        __syncthreads();
        x += y; tmp[t] = x;
        __syncthreads();
    }
    if (t < SCAN_NB) bsum[t] = x - v;           // exclusive block bases
}

__global__ __launch_bounds__(256) void scan3_kernel(int* __restrict__ offsets,
                                                    const int* __restrict__ bsum) {
    int i = blockIdx.x * 256 + threadIdx.x;
    if (i < NODES) offsets[i] += bsum[blockIdx.x];
}

__global__ __launch_bounds__(256) void perm_kernel(const int* __restrict__ eidx,
                                                   const int* __restrict__ offsets,
                                                   int* __restrict__ cursor,
                                                   int* __restrict__ perm) {
    int e = blockIdx.x * 256 + threadIdx.x;
    if (e < EDGES) {
        int s = eidx[e];
        int pos = offsets[s] + atomicAdd(&cursor[s], 1);
        perm[pos] = e;
    }
}

// ============================================================================
// Main: per-edge MLP + tensor product; SORTED=1 -> segmented scatter
// ============================================================================
template <int SORTED>
__global__ __launch_bounds__(256, 2) void tpconv_kernel(
    const float* __restrict__ node_attr,
    const float* __restrict__ edge_attr,
    const float* __restrict__ edge_sh,
    const int*   __restrict__ eidx,
    const float* __restrict__ W1,
    const float* __restrict__ b1,
    const float* __restrict__ W2,
    const float* __restrict__ b2,
    float* __restrict__ outp,          // [N][28] atomic accumulation target
    const int* __restrict__ perm,      // SORTED only
    float* __restrict__ cntf)          // legacy only
{
    __shared__ __align__(16) short w2t[NWT * 64];    // W2^T bf16, swizzled
    __shared__ float b2s[NWT];
    __shared__ __align__(16) short hbuf[4][16 * 64]; // per-wave h tile; reused as st[16][28] f32
    __shared__ float edata[4][16 * 53];              // per-wave per-edge coefficients
    __shared__ int   srcb[4][16];
    __shared__ int   eids[4][16];

    const int tid  = threadIdx.x;
    const int lane = tid & 63;
    const int wid  = tid >> 6;
    const int cl   = lane & 15;   // col within fragment
    const int qd   = lane >> 4;   // lane quad

    // ---- stage W2^T (bf16, swizzled) + b2 : once per block ----
    for (int f = tid; f < NWT * 64; f += 256) {
        int n = f >> 6, j = f & 63;
        int byte = SWZ(n * 128 + j * 2, n);
        w2t[byte >> 1] = f2bf(W2[j * NWT + n]);
    }
    for (int f = tid; f < NWT; f += 256) b2s[f] = b2[f];

    // ---- per-lane W1 fragments (B of GEMM1) + b1 ----
    float b1v[4];
    bf16x8 w1f[2][4];
    #pragma unroll
    for (int nt = 0; nt < 4; ++nt) {
        b1v[nt] = b1[nt * 16 + cl];
        #pragma unroll
        for (int ks = 0; ks < 2; ++ks) {
            bf16x8 fr;
            #pragma unroll
            for (int i = 0; i < 8; ++i) {
                int k = ks * 32 + qd * 8 + i;
                fr[i] = f2bf(W1[k * 64 + nt * 16 + cl]);
            }
            w1f[ks][nt] = fr;
        }
    }
    __syncthreads();

    const float INV3 = 0.57735026919f;      // 1/sqrt(3)
    const float CS_  = 0.17677669529f;      // (1/sqrt(16)) * (1/sqrt(2))
    const float CV_  = 0.35355339059f;      // (1/sqrt(4))  * (1/sqrt(2))

    const int tiles = EDGES / 16;           // 50000, exact
    for (int tile = blockIdx.x * 4 + wid; tile < tiles; tile += gridDim.x * 4) {
        const int ebase = tile * 16;

        // ---- per-edge coefficient precompute (lanes 0..15, one edge each) ----
        if (lane < 16) {
            const int slot = ebase + lane;
            const int e  = SORTED ? perm[slot] : slot;
            const int s  = eidx[e];
            const int dn = eidx[EDGES + e];
            srcb[wid][lane] = s;
            eids[wid][lane] = e;
            if (!SORTED) atomicAdd(&cntf[s], 1.0f);
            const float4 sh4 = *reinterpret_cast<const float4*>(edge_sh + (size_t)e * 4);
            float xs[16], xv[12];
            {
                const float4* xp = reinterpret_cast<const float4*>(node_attr + (size_t)dn * CH);
                float4 q0 = xp[0], q1 = xp[1], q2 = xp[2], q3 = xp[3], q4 = xp[4], q5 = xp[5], q6 = xp[6];
                xs[0]=q0.x; xs[1]=q0.y; xs[2]=q0.z; xs[3]=q0.w;
                xs[4]=q1.x; xs[5]=q1.y; xs[6]=q1.z; xs[7]=q1.w;
                xs[8]=q2.x; xs[9]=q2.y; xs[10]=q2.z; xs[11]=q2.w;
                xs[12]=q3.x; xs[13]=q3.y; xs[14]=q3.z; xs[15]=q3.w;
                xv[0]=q4.x; xv[1]=q4.y; xv[2]=q4.z; xv[3]=q4.w;
                xv[4]=q5.x; xv[5]=q5.y; xv[6]=q5.z; xv[7]=q5.w;
                xv[8]=q6.x; xv[9]=q6.y; xv[10]=q6.z; xv[11]=q6.w;
            }
            const float shs = sh4.x, sv0 = sh4.y, sv1 = sh4.z, sv2 = sh4.w;
            float* ed = &edata[wid][lane * 53];
            #pragma unroll
            for (int i = 0; i < 16; ++i) {
                ed[i]      = xs[i] * shs * CS_;   // a_s  (w_ss coeff)
                ed[20 + i] = xs[i] * CS_;         // b_s  (w_sv coeff)
            }
            #pragma unroll
            for (int v = 0; v < 4; ++v) {
                float dot = (xv[3*v] * sv0 + xv[3*v+1] * sv1 + xv[3*v+2] * sv2) * INV3;
                ed[16 + v] = dot * CV_;           // a_v  (w_vs coeff)
                ed[36 + 3*v + 0] = xv[3*v + 0] * shs * CV_;   // xvs (w_vv coeff)
                ed[36 + 3*v + 1] = xv[3*v + 1] * shs * CV_;
                ed[36 + 3*v + 2] = xv[3*v + 2] * shs * CV_;
            }
            ed[48] = sv0; ed[49] = sv1; ed[50] = sv2;
        }

        // ---- GEMM1 A fragments from global (row gather if sorted), f32 -> bf16 ----
        const int es = SORTED ? eids[wid][cl] : (ebase + cl);
        const float4* ap = reinterpret_cast<const float4*>(edge_attr + (size_t)es * 64);
        float4 a0 = ap[qd*2], a1 = ap[qd*2 + 1], a2 = ap[8 + qd*2], a3 = ap[8 + qd*2 + 1];
        bf16x8 af0, af1;
        af0[0]=f2bf(a0.x); af0[1]=f2bf(a0.y); af0[2]=f2bf(a0.z); af0[3]=f2bf(a0.w);
        af0[4]=f2bf(a1.x); af0[5]=f2bf(a1.y); af0[6]=f2bf(a1.z); af0[7]=f2bf(a1.w);
        af1[0]=f2bf(a2.x); af1[1]=f2bf(a2.y); af1[2]=f2bf(a2.z); af1[3]=f2bf(a2.w);
        af1[4]=f2bf(a3.x); af1[5]=f2bf(a3.y); af1[6]=f2bf(a3.z); af1[7]=f2bf(a3.w);

        // ---- GEMM1: h = relu(A @ W1 + b1), write bf16 h tile to LDS ----
        short* hb = hbuf[wid];
        #pragma unroll
        for (int nt = 0; nt < 4; ++nt) {
            f32x4 acc = { b1v[nt], b1v[nt], b1v[nt], b1v[nt] };
            acc = __builtin_amdgcn_mfma_f32_16x16x32_bf16(af0, w1f[0][nt], acc, 0, 0, 0);
            acc = __builtin_amdgcn_mfma_f32_16x16x32_bf16(af1, w1f[1][nt], acc, 0, 0, 0);
            #pragma unroll
            for (int r = 0; r < 4; ++r) {
                int m = qd * 4 + r;
                float hv = fmaxf(acc[r], 0.0f);
                int byte = SWZ(m * 128 + (nt * 16 + cl) * 2, m);
                hb[byte >> 1] = f2bf(hv);
            }
        }

        // ---- h fragments back (A of GEMM2); same-wave LDS, in-order ----
        bf16x8 h0 = *reinterpret_cast<bf16x8*>(reinterpret_cast<char*>(hb) + SWZ(cl * 128 + qd * 16, cl));
        bf16x8 h1 = *reinterpret_cast<bf16x8*>(reinterpret_cast<char*>(hb) + SWZ(cl * 128 + 64 + qd * 16, cl));

        // ---- GEMM2 over 25 column tiles, fused tensor-product consume ----
        f32x4 outs = {0.f, 0.f, 0.f, 0.f};
        f32x4 pacc = {0.f, 0.f, 0.f, 0.f};
        float qacc[4][3] = {{0.f,0.f,0.f},{0.f,0.f,0.f},{0.f,0.f,0.f},{0.f,0.f,0.f}};
        const float* edw = edata[wid];
        const char* wb = reinterpret_cast<const char*>(w2t);
        #pragma unroll
        for (int ct = 0; ct < 25; ++ct) {
            int n = ct * 16 + cl;
            bf16x8 bf0 = *reinterpret_cast<const bf16x8*>(wb + SWZ(n * 128 + qd * 16, n));
            bf16x8 bf1 = *reinterpret_cast<const bf16x8*>(wb + SWZ(n * 128 + 64 + qd * 16, n));
            float bb = b2s[n];
            f32x4 t = { bb, bb, bb, bb };
            t = __builtin_amdgcn_mfma_f32_16x16x32_bf16(h0, bf0, t, 0, 0, 0);
            t = __builtin_amdgcn_mfma_f32_16x16x32_bf16(h1, bf1, t, 0, 0, 0);
            if (ct < 16) {                       // w_ss
                #pragma unroll
                for (int r = 0; r < 4; ++r)
                    outs[r] += edw[(qd*4 + r) * 53 + ct] * t[r];
            } else if (ct < 20) {                // w_vs
                #pragma unroll
                for (int r = 0; r < 4; ++r)
                    outs[r] += edw[(qd*4 + r) * 53 + 16 + (ct - 16)] * t[r];
            } else if (ct < 24) {                // w_sv: P partial
                int il = cl >> 2;
                #pragma unroll
                for (int r = 0; r < 4; ++r)
                    pacc[r] += edw[(qd*4 + r) * 53 + 20 + 4*(ct - 20) + il] * t[r];
            } else {                             // w_vv: Q partial
                int v = cl >> 2;
                #pragma unroll
                for (int r = 0; r < 4; ++r) {
                    #pragma unroll
                    for (int d = 0; d < 3; ++d)
                        qacc[r][d] += edw[(qd*4 + r) * 53 + 36 + 3*v + d] * t[r];
                }
            }
        }

        // ---- butterfly-reduce P,Q over the 4 il/v sub-columns ----
        #pragma unroll
        for (int r = 0; r < 4; ++r) {
            float p = pacc[r];
            p += __shfl_xor(p, 4);
            p += __shfl_xor(p, 8);
            pacc[r] = p;
            #pragma unroll
            for (int d = 0; d < 3; ++d) {
                float q = qacc[r][d];
                q += __shfl_xor(q, 4);
                q += __shfl_xor(q, 8);
                qacc[r][d] = q;
            }
        }

        if (SORTED) {
            // ---- assemble 16x28 tile in LDS (reuse hbuf region) ----
            float* stf = reinterpret_cast<float*>(hb);
            #pragma unroll
            for (int r = 0; r < 4; ++r)
                stf[(qd*4 + r) * CH + cl] = outs[r];
            if (cl < 12) {
                int o = cl & 3, d = cl >> 2;
                #pragma unroll
                for (int r = 0; r < 4; ++r) {
                    int m = qd * 4 + r;
                    float qv = (d == 0) ? qacc[r][0] : ((d == 1) ? qacc[r][1] : qacc[r][2]);
                    stf[m * CH + 16 + o * 3 + d] = edw[m * 53 + 48 + d] * pacc[r] + qv;
                }
            }
            // ---- segmented scatter: runs of equal src -> one atomic per run/channel ----
            if (lane < CH) {
                int cur = srcb[wid][0];
                float acc2 = 0.0f;
                for (int m = 0; m < 16; ++m) {
                    int s = srcb[wid][m];
                    if (s != cur) {
                        atomicAdd(&outp[(size_t)cur * CH + lane], acc2);
                        acc2 = 0.0f; cur = s;
                    }
                    acc2 += stf[m * CH + lane];
                }
                atomicAdd(&outp[(size_t)cur * CH + lane], acc2);
            }
        } else {
            // ---- legacy per-edge atomic scatter ----
            #pragma unroll
            for (int r = 0; r < 4; ++r) {
                int m = qd * 4 + r;
                int s = srcb[wid][m];
                atomicAdd(&outp[(size_t)s * CH + cl], outs[r]);
            }
            if (cl < 12) {
                int o = cl & 3, d = cl >> 2;
                #pragma unroll
                for (int r = 0; r < 4; ++r) {
                    int m = qd * 4 + r;
                    int s = srcb[wid][m];
                    float qv = (d == 0) ? qacc[r][0] : ((d == 1) ? qacc[r][1] : qacc[r][2]);
                    atomicAdd(&outp[(size_t)s * CH + 16 + o * 3 + d],
                              edw[m * 53 + 48 + d] * pacc[r] + qv);
                }
            }
        }
    }
}

__global__ __launch_bounds__(256) void finalize_sorted(float* __restrict__ out,
                                                       const int* __restrict__ counts,
                                                       const float* __restrict__ node_attr) {
    int idx = blockIdx.x * 256 + threadIdx.x;
    if (idx < NODES * CH) {
        int n = idx / CH;
        out[idx] = out[idx] / fmaxf((float)counts[n], 1.0f) + node_attr[idx];
    }
}

__global__ __launch_bounds__(256) void finalize_legacy(float* __restrict__ out,
                                                       const float* __restrict__ cnt,
                                                       const float* __restrict__ node_attr) {
    int idx = blockIdx.x * 256 + threadIdx.x;
    if (idx < NODES * CH) {
        int n = idx / CH;
        out[idx] = out[idx] / fmaxf(cnt[n], 1.0f) + node_attr[idx];
    }
}

extern "C" void kernel_launch(void* const* d_in, const int* in_sizes, int n_in,
                              void* d_out, int out_size, void* d_ws, size_t ws_size,
                              hipStream_t stream) {
    const float* node_attr = (const float*)d_in[0];
    const float* edge_attr = (const float*)d_in[1];
    const float* edge_sh   = (const float*)d_in[2];
    const int*   eidx      = (const int*)d_in[3];
    const float* W1 = (const float*)d_in[4];
    const float* b1 = (const float*)d_in[5];
    const float* W2 = (const float*)d_in[6];
    const float* b2 = (const float*)d_in[7];
    float* out = (float*)d_out;

    // ws layout (bytes): counts@0, offsets@204800, cursor@409600, bsum@614400, perm@616448
    const size_t OFF_OFFSETS = 204800;
    const size_t OFF_CURSOR  = 409600;
    const size_t OFF_BSUM    = 614400;
    const size_t OFF_PERM    = 616448;
    const size_t TOTAL_NEED  = OFF_PERM + (size_t)EDGES * sizeof(int);   // ~3.82 MB

    const int EB = (EDGES + 255) / 256;  // 3125

    if (ws_size >= TOTAL_NEED) {
        int* counts  = (int*)d_ws;
        int* offsets = (int*)((char*)d_ws + OFF_OFFSETS);
        int* cursor  = (int*)((char*)d_ws + OFF_CURSOR);
        int* bsum    = (int*)((char*)d_ws + OFF_BSUM);
        int* perm    = (int*)((char*)d_ws + OFF_PERM);

        hipMemsetAsync(counts, 0, NODES * sizeof(int), stream);
        hipMemsetAsync(cursor, 0, NODES * sizeof(int), stream);
        hipMemsetAsync(d_out, 0, (size_t)NODES * CH * sizeof(float), stream);

        hist_kernel<<<EB, 256, 0, stream>>>(eidx, counts);
        scan1_kernel<<<SCAN_NB, 256, 0, stream>>>(counts, offsets, bsum);
        scan2_kernel<<<1, 256, 0, stream>>>(bsum);
        scan3_kernel<<<SCAN_NB, 256, 0, stream>>>(offsets, bsum);
        perm_kernel<<<EB, 256, 0, stream>>>(eidx, offsets, cursor, perm);

        tpconv_kernel<1><<<512, 256, 0, stream>>>(node_attr, edge_attr, edge_sh, eidx,
                                                  W1, b1, W2, b2, out, perm, nullptr);
        finalize_sorted<<<(NODES * CH + 255) / 256, 256, 0, stream>>>(out, counts, node_attr);
    } else {
        float* cntf = (float*)d_ws;
        hipMemsetAsync(d_out, 0, (size_t)NODES * CH * sizeof(float), stream);
        hipMemsetAsync(d_ws, 0, NODES * sizeof(float), stream);
        tpconv_kernel<0><<<512, 256, 0, stream>>>(node_attr, edge_attr, edge_sh, eidx,
                                                  W1, b1, W2, b2, out, nullptr, cntf);
        finalize_legacy<<<(NODES * CH + 255) / 256, 256, 0, stream>>>(out, cntf, node_attr);
    }
}